// Round 1
// baseline (1118.362 us; speedup 1.0000x reference)
//
#include <hip/hip_runtime.h>
#include <hip/hip_bf16.h>

#define NB 16
#define NW 64
#define NV 64
#define ND 256
#define NR 64
#define NN 4096
#define NEGV -10000000000.0f

// ---------- dtype-flexible helpers (flag: 1 = bf16 data, 0 = f32 data) ----------
__device__ inline float cvt(const void* p, int idx, int flag) {
  if (flag) return __bfloat162float(((const __hip_bfloat16*)p)[idx]);
  return ((const float*)p)[idx];
}
__device__ inline void stv(void* p, int idx, float v, int flag) {
  if (flag) ((__hip_bfloat16*)p)[idx] = __float2bfloat16(v);
  else ((float*)p)[idx] = v;
}
// tuple_vec scratch storage (tupbf: 1 = bf16 in ws, 0 = f32 in ws)
__device__ inline float ldt(const void* p, int idx, int tupbf) {
  if (tupbf) return __bfloat162float(((const __hip_bfloat16*)p)[idx]);
  return ((const float*)p)[idx];
}
__device__ inline void stt(void* p, int idx, float v, int tupbf) {
  if (tupbf) ((__hip_bfloat16*)p)[idx] = __float2bfloat16(v);
  else ((float*)p)[idx] = v;
}
__device__ inline float tanh_fast(float x) {
  float ax = fabsf(x);
  float e = __expf(-2.f * ax);
  float r = (1.f - e) / (1.f + e);
  return copysignf(r, x);
}

// ---------- K0: detect input dtype (bf16 vs f32) ----------
__global__ void k_detect(const unsigned int* embw, int* flagp) {
  __shared__ float red[256];
  int t = threadIdx.x;
  float mx = 0.f;
  for (int i = t; i < 1024; i += 256) {
    unsigned int w = embw[i];
    unsigned int fb = (w & 0xffffu) << 16;   // low 16 bits as bf16 -> f32 bits
    float a = fabsf(__uint_as_float(fb));
    if (!(a < 1e9f)) a = 1e9f;               // NaN/Inf -> big
    mx = fmaxf(mx, a);
  }
  red[t] = mx;
  __syncthreads();
  for (int s = 128; s > 0; s >>= 1) {
    if (t < s) red[t] = fmaxf(red[t], red[t + s]);
    __syncthreads();
  }
  if (t == 0) flagp[0] = (red[0] < 1000.f) ? 1 : 0;
}

// ---------- K1: build relaT[d*64+r] = rela[r, d] in f32 ----------
__global__ void k_relat(const void* rela, float* relaT, const int* flagp) {
  int flag = flagp[0];
  int r = blockIdx.x;      // 64 blocks
  int d = threadIdx.x;     // 256
  relaT[d * NR + r] = cvt(rela, r * ND + d, flag);
}

// ---------- K2: gather A = emb[head_ctx], B = emb[tail_ctx] (f32) ----------
__global__ void k_gather(const int* head, const int* tail, const void* emb,
                         float* Af, float* Bf, const int* flagp) {
  int flag = flagp[0];
  int row = blockIdx.x;    // 2048
  int t = threadIdx.x;     // 256
  if (row < NB * NW) {
    int ix = head[row];
    Af[row * ND + t] = cvt(emb, ix * ND + t, flag);
  } else {
    int rr = row - NB * NW;
    int ix = tail[rr];
    Bf[rr * ND + t] = cvt(emb, ix * ND + t, flag);
  }
}

// ---------- K3: Ah = A@Wa + fc_b, Bh = B@Wb, RW = rela@Wc ----------
__global__ void k_premm(const float* Af, const float* Bf, const void* rela,
                        const void* fcw, const void* fcb,
                        float* Ah, float* Bh, float* RW, const int* flagp) {
  int flag = flagp[0];
  int row = blockIdx.x;    // 2112 = 1024 + 1024 + 64
  int t = threadIdx.x;     // 256
  __shared__ float rl[ND];
  float* dst;
  int wbase, addb = 0;
  if (row < 1024) {
    rl[t] = Af[row * ND + t];
    wbase = 0; dst = Ah + row * ND; addb = 1;
  } else if (row < 2048) {
    int rr = row - 1024;
    rl[t] = Bf[rr * ND + t];
    wbase = ND; dst = Bh + rr * ND;
  } else {
    int rr = row - 2048;
    rl[t] = cvt(rela, rr * ND + t, flag);
    wbase = 2 * ND; dst = RW + rr * ND;
  }
  __syncthreads();
  float acc = 0.f;
  for (int k = 0; k < ND; ++k)
    acc += rl[k] * cvt(fcw, (wbase + k) * ND + t, flag);
  if (addb) acc += cvt(fcb, t, flag);
  dst[t] = acc;
}

// ---------- K4: scores -> mask -> softmax -> norm_scores (ws f32 + d_out) ----------
__global__ void k_scores(const float* Af, const float* Bf, const float* relaT,
                         float* nsw, void* out, const int* flagp) {
  int flag = flagp[0];
  int bi = blockIdx.x;         // 1024 = b*64 + i
  int b = bi >> 6;
  int t = threadIdx.x;         // 256
  int r = t & 63;
  int q = t >> 6;
  __shared__ float Al[ND];
  __shared__ float Bl[ND];
  __shared__ float part[256];
  Al[t] = Af[bi * ND + t];
  __syncthreads();
  float preR[64];
#pragma unroll
  for (int i2 = 0; i2 < 64; ++i2) {
    int d = q * 64 + i2;
    preR[i2] = Al[d] * relaT[d * NR + r];
  }
  for (int j = 0; j < NV; ++j) {
    Bl[t] = Bf[(b * NV + j) * ND + t];
    __syncthreads();
    float acc = 0.f;
#pragma unroll
    for (int i2 = 0; i2 < 64; ++i2)
      acc += preR[i2] * Bl[q * 64 + i2];
    part[t] = acc;
    __syncthreads();
    if (t < 64) {
      float s = part[t] + part[64 + t] + part[128 + t] + part[192 + t];
      float nullv = __shfl(s, 63, 64);
      float m = (s <= nullv) ? NEGV : s;
      float mx = m;
#pragma unroll
      for (int o = 32; o > 0; o >>= 1) mx = fmaxf(mx, __shfl_xor(mx, o, 64));
      float e = __expf(m - mx);
      float sum = e;
#pragma unroll
      for (int o = 32; o > 0; o >>= 1) sum += __shfl_xor(sum, o, 64);
      float ns = e / sum;
      int nidx = (bi * 64 + j) * 64 + t;   // ((b*N + i*64 + j)*R + r)
      nsw[nidx] = ns;
      stv(out, 16 + NB * NN + nidx, ns, flag);
    }
    __syncthreads();
  }
}

// ---------- K5: tuple_vec = tanh(Ah + Bh + ns@RW) ----------
__global__ void k_tuple(const float* Ah, const float* Bh, const float* RW,
                        const float* nsw, void* tup, const int* flagp, int tupbf) {
  int bi = blockIdx.x;       // 1024
  int b = bi >> 6;
  int t = threadIdx.x;       // 256
  __shared__ float nsl[NR];
  float RWc[64];
#pragma unroll
  for (int r = 0; r < 64; ++r) RWc[r] = RW[r * ND + t];
  float base0 = Ah[bi * ND + t];
  for (int j = 0; j < NV; ++j) {
    if (t < 64) nsl[t] = nsw[(bi * 64 + j) * 64 + t];
    __syncthreads();
    float acc = base0 + Bh[(b * NV + j) * ND + t];
#pragma unroll
    for (int r = 0; r < 64; ++r) acc += nsl[r] * RWc[r];
    stt(tup, (bi * 64 + j) * ND + t, tanh_fast(acc), tupbf);
    __syncthreads();
  }
}

// ---------- K6: att_raw = tanh(tuple@W1 + b1)@w2 + b2 ----------
__global__ void __launch_bounds__(512) k_att(const void* tup, const void* w1,
                                             const void* b1, const void* w2,
                                             const void* b2p, float* att_raw,
                                             const int* flagp, int tupbf) {
  int flag = flagp[0];
  int bi = blockIdx.x;        // 1024
  int t = threadIdx.x;        // 512
  int d = t & 255;
  int h = t >> 8;
  float W1c[128];
#pragma unroll
  for (int k = 0; k < 128; ++k)
    W1c[k] = cvt(w1, (h * 128 + k) * ND + d, flag);
  float b1r = 0.f, w2r = 0.f;
  if (t < 256) { b1r = cvt(b1, t, flag); w2r = cvt(w2, t, flag); }
  float b2v = cvt(b2p, 0, flag);
  __shared__ float tl[ND];
  __shared__ float part[512];
  __shared__ float wsum[4];
  for (int j = 0; j < NV; ++j) {
    int n = bi * 64 + j;
    if (t < 256) tl[t] = ldt(tup, n * ND + t, tupbf);
    __syncthreads();
    float acc = 0.f;
#pragma unroll
    for (int k = 0; k < 128; ++k)
      acc += tl[h * 128 + k] * W1c[k];
    part[t] = acc;
    __syncthreads();
    if (t < 256) {
      float t1 = tanh_fast(part[t] + part[256 + t] + b1r);
      float v = t1 * w2r;
#pragma unroll
      for (int o = 32; o > 0; o >>= 1) v += __shfl_xor(v, o, 64);
      if ((t & 63) == 0) wsum[t >> 6] = v;
    }
    __syncthreads();
    if (t == 0) att_raw[n] = wsum[0] + wsum[1] + wsum[2] + wsum[3] + b2v;
    __syncthreads();
  }
}

// ---------- K7: att softmax over N, fuse, logits ----------
__global__ void k_fuse(const float* att_raw, const void* tup, const void* outw,
                       const void* outb, float* attn, void* out,
                       const int* flagp, int tupbf) {
  int flag = flagp[0];
  int b = blockIdx.x;         // 16
  int t = threadIdx.x;        // 256
  __shared__ float red[256];
  __shared__ float al[256];
  // max
  float mx = -3.4e38f;
  for (int n = t; n < NN; n += 256) mx = fmaxf(mx, att_raw[b * NN + n]);
  red[t] = mx;
  __syncthreads();
  for (int s = 128; s > 0; s >>= 1) {
    if (t < s) red[t] = fmaxf(red[t], red[t + s]);
    __syncthreads();
  }
  float M = red[0];
  __syncthreads();
  // sum
  float sm = 0.f;
  for (int n = t; n < NN; n += 256) sm += __expf(att_raw[b * NN + n] - M);
  red[t] = sm;
  __syncthreads();
  for (int s = 128; s > 0; s >>= 1) {
    if (t < s) red[t] += red[t + s];
    __syncthreads();
  }
  float Z = red[0];
  __syncthreads();
  for (int n = t; n < NN; n += 256) {
    float a = __expf(att_raw[b * NN + n] - M) / Z;
    attn[b * NN + n] = a;
    stv(out, 16 + b * NN + n, a, flag);
  }
  __syncthreads();
  // fuse: thread = d
  float acc = 0.f;
  for (int c0 = 0; c0 < NN; c0 += 256) {
    al[t] = attn[b * NN + c0 + t];
    __syncthreads();
    for (int c = 0; c < 256; ++c)
      acc += al[c] * ldt(tup, (b * NN + c0 + c) * ND + t, tupbf);
    __syncthreads();
  }
  float v = acc * cvt(outw, t, flag);
  red[t] = v;
  __syncthreads();
  for (int s = 128; s > 0; s >>= 1) {
    if (t < s) red[t] += red[t + s];
    __syncthreads();
  }
  if (t == 0) stv(out, b, red[0] + cvt(outb, 0, flag), flag);
}

// ---------- host ----------
extern "C" void kernel_launch(void* const* d_in, const int* in_sizes, int n_in,
                              void* d_out, int out_size, void* d_ws, size_t ws_size,
                              hipStream_t stream) {
  const int* head = (const int*)d_in[0];
  const int* tail = (const int*)d_in[1];
  const void* emb = d_in[2];
  const void* rela = d_in[3];
  const void* fcw = d_in[4];
  const void* fcb = d_in[5];
  const void* w1 = d_in[6];
  const void* b1 = d_in[7];
  const void* w2 = d_in[8];
  const void* b2 = d_in[9];
  const void* outw = d_in[10];
  const void* outb = d_in[11];

  float* ws = (float*)d_ws;
  int* flagp = (int*)d_ws;
  const size_t O_RELAT = 16;
  const size_t O_AF = O_RELAT + 16384;
  const size_t O_BF = O_AF + 262144;
  const size_t O_AH = O_BF + 262144;
  const size_t O_BH = O_AH + 262144;
  const size_t O_RW = O_BH + 262144;
  const size_t O_NS = O_RW + 16384;
  const size_t O_ATTR = O_NS + 4194304;
  const size_t O_ATTN = O_ATTR + 65536;
  const size_t O_TUP = O_ATTN + 65536;
  // tuple_vec: f32 if workspace allows (B*N*D = 16.8M floats), else bf16
  int tupbf = (ws_size >= (O_TUP + 16777216) * 4) ? 0 : 1;

  float* relaT = ws + O_RELAT;
  float* Af = ws + O_AF;
  float* Bf = ws + O_BF;
  float* Ah = ws + O_AH;
  float* Bh = ws + O_BH;
  float* RW = ws + O_RW;
  float* nsw = ws + O_NS;
  float* attr = ws + O_ATTR;
  float* attn = ws + O_ATTN;
  void* tup = (void*)(ws + O_TUP);

  hipLaunchKernelGGL(k_detect, dim3(1), dim3(256), 0, stream,
                     (const unsigned int*)emb, flagp);
  hipLaunchKernelGGL(k_relat, dim3(64), dim3(256), 0, stream, rela, relaT, flagp);
  hipLaunchKernelGGL(k_gather, dim3(2048), dim3(256), 0, stream,
                     head, tail, emb, Af, Bf, flagp);
  hipLaunchKernelGGL(k_premm, dim3(2112), dim3(256), 0, stream,
                     Af, Bf, rela, fcw, fcb, Ah, Bh, RW, flagp);
  hipLaunchKernelGGL(k_scores, dim3(1024), dim3(256), 0, stream,
                     Af, Bf, relaT, nsw, d_out, flagp);
  hipLaunchKernelGGL(k_tuple, dim3(1024), dim3(256), 0, stream,
                     Ah, Bh, RW, nsw, tup, flagp, tupbf);
  hipLaunchKernelGGL(k_att, dim3(1024), dim3(512), 0, stream,
                     tup, w1, b1, w2, b2, attr, flagp, tupbf);
  hipLaunchKernelGGL(k_fuse, dim3(16), dim3(256), 0, stream,
                     attr, tup, outw, outb, attn, d_out, flagp, tupbf);
}

// Round 2
// 747.381 us; speedup vs baseline: 1.4964x; 1.4964x over previous
//
#include <hip/hip_runtime.h>
#include <hip/hip_bf16.h>

#define NB 16
#define NW 64
#define NV 64
#define ND 256
#define NR 64
#define NN 4096
#define NEGV -10000000000.0f

// ---------- dtype-flexible helpers (flag: 1 = bf16 data, 0 = f32 data) ----------
__device__ inline float cvt(const void* p, int idx, int flag) {
  if (flag) return __bfloat162float(((const __hip_bfloat16*)p)[idx]);
  return ((const float*)p)[idx];
}
__device__ inline void stv(void* p, int idx, float v, int flag) {
  if (flag) ((__hip_bfloat16*)p)[idx] = __float2bfloat16(v);
  else ((float*)p)[idx] = v;
}
// tuple_vec scratch storage (tupbf: 1 = bf16 in ws, 0 = f32 in ws)
__device__ inline float ldt(const void* p, int idx, int tupbf) {
  if (tupbf) return __bfloat162float(((const __hip_bfloat16*)p)[idx]);
  return ((const float*)p)[idx];
}
__device__ inline void stt(void* p, int idx, float v, int tupbf) {
  if (tupbf) ((__hip_bfloat16*)p)[idx] = __float2bfloat16(v);
  else ((float*)p)[idx] = v;
}
__device__ inline float tanh_fast(float x) {
  float ax = fabsf(x);
  float e = __expf(-2.f * ax);
  float r = (1.f - e) / (1.f + e);
  return copysignf(r, x);
}

// ---------- K0: detect input dtype (bf16 vs f32) ----------
__global__ void k_detect(const unsigned int* embw, int* flagp) {
  __shared__ float red[256];
  int t = threadIdx.x;
  float mx = 0.f;
  for (int i = t; i < 1024; i += 256) {
    unsigned int w = embw[i];
    unsigned int fb = (w & 0xffffu) << 16;   // low 16 bits as bf16 -> f32 bits
    float a = fabsf(__uint_as_float(fb));
    if (!(a < 1e9f)) a = 1e9f;               // NaN/Inf -> big
    mx = fmaxf(mx, a);
  }
  red[t] = mx;
  __syncthreads();
  for (int s = 128; s > 0; s >>= 1) {
    if (t < s) red[t] = fmaxf(red[t], red[t + s]);
    __syncthreads();
  }
  if (t == 0) flagp[0] = (red[0] < 1000.f) ? 1 : 0;
}

// ---------- K1: build relaT[d*64+r] = rela[r, d] in f32 ----------
__global__ void k_relat(const void* rela, float* relaT, const int* flagp) {
  int flag = flagp[0];
  int r = blockIdx.x;      // 64 blocks
  int d = threadIdx.x;     // 256
  relaT[d * NR + r] = cvt(rela, r * ND + d, flag);
}

// ---------- K2: gather A = emb[head_ctx], B = emb[tail_ctx] (f32) ----------
__global__ void k_gather(const int* head, const int* tail, const void* emb,
                         float* Af, float* Bf, const int* flagp) {
  int flag = flagp[0];
  int row = blockIdx.x;    // 2048
  int t = threadIdx.x;     // 256
  if (row < NB * NW) {
    int ix = head[row];
    Af[row * ND + t] = cvt(emb, ix * ND + t, flag);
  } else {
    int rr = row - NB * NW;
    int ix = tail[rr];
    Bf[rr * ND + t] = cvt(emb, ix * ND + t, flag);
  }
}

// ---------- K3: Ah = A@Wa + fc_b, Bh = B@Wb, RW = rela@Wc ----------
__global__ void k_premm(const float* Af, const float* Bf, const void* rela,
                        const void* fcw, const void* fcb,
                        float* Ah, float* Bh, float* RW, const int* flagp) {
  int flag = flagp[0];
  int row = blockIdx.x;    // 2112 = 1024 + 1024 + 64
  int t = threadIdx.x;     // 256
  __shared__ float rl[ND];
  float* dst;
  int wbase, addb = 0;
  if (row < 1024) {
    rl[t] = Af[row * ND + t];
    wbase = 0; dst = Ah + row * ND; addb = 1;
  } else if (row < 2048) {
    int rr = row - 1024;
    rl[t] = Bf[rr * ND + t];
    wbase = ND; dst = Bh + rr * ND;
  } else {
    int rr = row - 2048;
    rl[t] = cvt(rela, rr * ND + t, flag);
    wbase = 2 * ND; dst = RW + rr * ND;
  }
  __syncthreads();
  float acc = 0.f;
  for (int k = 0; k < ND; ++k)
    acc += rl[k] * cvt(fcw, (wbase + k) * ND + t, flag);
  if (addb) acc += cvt(fcb, t, flag);
  dst[t] = acc;
}

// ---------- K4: scores -> mask -> softmax -> norm_scores (ws f32 + d_out) ----------
__global__ void k_scores(const float* Af, const float* Bf, const float* relaT,
                         float* nsw, void* out, const int* flagp) {
  int flag = flagp[0];
  int bi = blockIdx.x;         // 1024 = b*64 + i
  int b = bi >> 6;
  int t = threadIdx.x;         // 256
  int r = t & 63;
  int q = t >> 6;
  __shared__ float Al[ND];
  __shared__ float Bl[ND];
  __shared__ float part[256];
  Al[t] = Af[bi * ND + t];
  __syncthreads();
  float preR[64];
#pragma unroll
  for (int i2 = 0; i2 < 64; ++i2) {
    int d = q * 64 + i2;
    preR[i2] = Al[d] * relaT[d * NR + r];
  }
  for (int j = 0; j < NV; ++j) {
    Bl[t] = Bf[(b * NV + j) * ND + t];
    __syncthreads();
    float acc = 0.f;
#pragma unroll
    for (int i2 = 0; i2 < 64; ++i2)
      acc += preR[i2] * Bl[q * 64 + i2];
    part[t] = acc;
    __syncthreads();
    if (t < 64) {
      float s = part[t] + part[64 + t] + part[128 + t] + part[192 + t];
      float nullv = __shfl(s, 63, 64);
      float m = (s <= nullv) ? NEGV : s;
      float mx = m;
#pragma unroll
      for (int o = 32; o > 0; o >>= 1) mx = fmaxf(mx, __shfl_xor(mx, o, 64));
      float e = __expf(m - mx);
      float sum = e;
#pragma unroll
      for (int o = 32; o > 0; o >>= 1) sum += __shfl_xor(sum, o, 64);
      float ns = e / sum;
      int nidx = (bi * 64 + j) * 64 + t;   // ((b*N + i*64 + j)*R + r)
      nsw[nidx] = ns;
      stv(out, 16 + NB * NN + nidx, ns, flag);
    }
    __syncthreads();
  }
}

// ---------- K5: tuple_vec = tanh(Ah + Bh + ns@RW) ----------
__global__ void k_tuple(const float* Ah, const float* Bh, const float* RW,
                        const float* nsw, void* tup, const int* flagp, int tupbf) {
  int bi = blockIdx.x;       // 1024
  int b = bi >> 6;
  int t = threadIdx.x;       // 256
  __shared__ float nsl[NR];
  float RWc[64];
#pragma unroll
  for (int r = 0; r < 64; ++r) RWc[r] = RW[r * ND + t];
  float base0 = Ah[bi * ND + t];
  for (int j = 0; j < NV; ++j) {
    if (t < 64) nsl[t] = nsw[(bi * 64 + j) * 64 + t];
    __syncthreads();
    float acc = base0 + Bh[(b * NV + j) * ND + t];
#pragma unroll
    for (int r = 0; r < 64; ++r) acc += nsl[r] * RWc[r];
    stt(tup, (bi * 64 + j) * ND + t, tanh_fast(acc), tupbf);
    __syncthreads();
  }
}

// ---------- K6: att_raw = tanh(tuple@W1 + b1)@w2 + b2 ; dot = tuple@out_w ----------
__global__ void __launch_bounds__(512) k_att(const void* tup, const void* w1,
                                             const void* b1, const void* w2,
                                             const void* b2p, const void* outw,
                                             float* att_raw, float* dotv,
                                             const int* flagp, int tupbf) {
  int flag = flagp[0];
  int bi = blockIdx.x;        // 1024
  int t = threadIdx.x;        // 512
  int d = t & 255;
  int h = t >> 8;
  float W1c[128];
#pragma unroll
  for (int k = 0; k < 128; ++k)
    W1c[k] = cvt(w1, (h * 128 + k) * ND + d, flag);
  float b1r = 0.f, w2r = 0.f, owr = 0.f;
  if (t < 256) {
    b1r = cvt(b1, t, flag);
    w2r = cvt(w2, t, flag);
    owr = cvt(outw, t, flag);
  }
  float b2v = cvt(b2p, 0, flag);
  __shared__ float tl[ND];
  __shared__ float part[512];
  __shared__ float wsum[4];
  __shared__ float wsum2[4];
  for (int j = 0; j < NV; ++j) {
    int n = bi * 64 + j;       // == b*4096 + i*64 + j (global n index)
    if (t < 256) tl[t] = ldt(tup, n * ND + t, tupbf);
    __syncthreads();
    float acc = 0.f;
#pragma unroll
    for (int k = 0; k < 128; ++k)
      acc += tl[h * 128 + k] * W1c[k];
    part[t] = acc;
    __syncthreads();
    if (t < 256) {
      float t1 = tanh_fast(part[t] + part[256 + t] + b1r);
      float v = t1 * w2r;
#pragma unroll
      for (int o = 32; o > 0; o >>= 1) v += __shfl_xor(v, o, 64);
      if ((t & 63) == 0) wsum[t >> 6] = v;
      // dot = tuple . out_w (reuses tl in LDS)
      float v2 = tl[t] * owr;
#pragma unroll
      for (int o = 32; o > 0; o >>= 1) v2 += __shfl_xor(v2, o, 64);
      if ((t & 63) == 0) wsum2[t >> 6] = v2;
    }
    __syncthreads();
    if (t == 0) {
      att_raw[n] = wsum[0] + wsum[1] + wsum[2] + wsum[3] + b2v;
      dotv[n] = wsum2[0] + wsum2[1] + wsum2[2] + wsum2[3];
    }
    __syncthreads();
  }
}

// ---------- K7: att softmax over N -> att_norms out; logits = sum attn*dot + b ----------
__global__ void k_fuse(const float* att_raw, const float* dotv,
                       const void* outb, void* out, const int* flagp) {
  int flag = flagp[0];
  int b = blockIdx.x;         // 16
  int t = threadIdx.x;        // 256
  __shared__ float red[256];
  float vals[16];
  float mx = -3.4e38f;
#pragma unroll
  for (int c = 0; c < 16; ++c) {
    vals[c] = att_raw[b * NN + c * 256 + t];
    mx = fmaxf(mx, vals[c]);
  }
  red[t] = mx;
  __syncthreads();
  for (int s = 128; s > 0; s >>= 1) {
    if (t < s) red[t] = fmaxf(red[t], red[t + s]);
    __syncthreads();
  }
  float M = red[0];
  __syncthreads();
  float sm = 0.f;
#pragma unroll
  for (int c = 0; c < 16; ++c) {
    vals[c] = __expf(vals[c] - M);
    sm += vals[c];
  }
  red[t] = sm;
  __syncthreads();
  for (int s = 128; s > 0; s >>= 1) {
    if (t < s) red[t] += red[t + s];
    __syncthreads();
  }
  float Z = red[0];
  __syncthreads();
  float acc = 0.f;
#pragma unroll
  for (int c = 0; c < 16; ++c) {
    int n = c * 256 + t;
    float a = vals[c] / Z;
    stv(out, 16 + b * NN + n, a, flag);
    acc += a * dotv[b * NN + n];
  }
  red[t] = acc;
  __syncthreads();
  for (int s = 128; s > 0; s >>= 1) {
    if (t < s) red[t] += red[t + s];
    __syncthreads();
  }
  if (t == 0) stv(out, b, red[0] + cvt(outb, 0, flag), flag);
}

// ---------- host ----------
extern "C" void kernel_launch(void* const* d_in, const int* in_sizes, int n_in,
                              void* d_out, int out_size, void* d_ws, size_t ws_size,
                              hipStream_t stream) {
  const int* head = (const int*)d_in[0];
  const int* tail = (const int*)d_in[1];
  const void* emb = d_in[2];
  const void* rela = d_in[3];
  const void* fcw = d_in[4];
  const void* fcb = d_in[5];
  const void* w1 = d_in[6];
  const void* b1 = d_in[7];
  const void* w2 = d_in[8];
  const void* b2 = d_in[9];
  const void* outw = d_in[10];
  const void* outb = d_in[11];

  float* ws = (float*)d_ws;
  int* flagp = (int*)d_ws;
  const size_t O_RELAT = 16;
  const size_t O_AF = O_RELAT + 16384;
  const size_t O_BF = O_AF + 262144;
  const size_t O_AH = O_BF + 262144;
  const size_t O_BH = O_AH + 262144;
  const size_t O_RW = O_BH + 262144;
  const size_t O_NS = O_RW + 16384;
  const size_t O_ATTR = O_NS + 4194304;
  const size_t O_DOT = O_ATTR + 65536;
  const size_t O_TUP = O_DOT + 65536;
  // tuple_vec: f32 if workspace allows (B*N*D = 16.8M floats), else bf16
  int tupbf = (ws_size >= (O_TUP + 16777216) * 4) ? 0 : 1;

  float* relaT = ws + O_RELAT;
  float* Af = ws + O_AF;
  float* Bf = ws + O_BF;
  float* Ah = ws + O_AH;
  float* Bh = ws + O_BH;
  float* RW = ws + O_RW;
  float* nsw = ws + O_NS;
  float* attr = ws + O_ATTR;
  float* dotv = ws + O_DOT;
  void* tup = (void*)(ws + O_TUP);

  hipLaunchKernelGGL(k_detect, dim3(1), dim3(256), 0, stream,
                     (const unsigned int*)emb, flagp);
  hipLaunchKernelGGL(k_relat, dim3(64), dim3(256), 0, stream, rela, relaT, flagp);
  hipLaunchKernelGGL(k_gather, dim3(2048), dim3(256), 0, stream,
                     head, tail, emb, Af, Bf, flagp);
  hipLaunchKernelGGL(k_premm, dim3(2112), dim3(256), 0, stream,
                     Af, Bf, rela, fcw, fcb, Ah, Bh, RW, flagp);
  hipLaunchKernelGGL(k_scores, dim3(1024), dim3(256), 0, stream,
                     Af, Bf, relaT, nsw, d_out, flagp);
  hipLaunchKernelGGL(k_tuple, dim3(1024), dim3(256), 0, stream,
                     Ah, Bh, RW, nsw, tup, flagp, tupbf);
  hipLaunchKernelGGL(k_att, dim3(1024), dim3(512), 0, stream,
                     tup, w1, b1, w2, b2, outw, attr, dotv, flagp, tupbf);
  hipLaunchKernelGGL(k_fuse, dim3(16), dim3(256), 0, stream,
                     attr, dotv, outb, d_out, flagp);
}

// Round 3
// 374.857 us; speedup vs baseline: 2.9834x; 1.9938x over previous
//
#include <hip/hip_runtime.h>
#include <hip/hip_bf16.h>

#define NB 16
#define NW 64
#define NV 64
#define ND 256
#define NR 64
#define NN 4096
#define NEGV -10000000000.0f

typedef __attribute__((ext_vector_type(8))) short short8;
typedef __attribute__((ext_vector_type(4))) float f32x4;

__device__ inline float cvt(const void* p, int idx, int flag) {
  if (flag) return __bfloat162float(((const __hip_bfloat16*)p)[idx]);
  return ((const float*)p)[idx];
}
__device__ inline void stv(void* p, int idx, float v, int flag) {
  if (flag) ((__hip_bfloat16*)p)[idx] = __float2bfloat16(v);
  else ((float*)p)[idx] = v;
}
__device__ inline float bf2f(short s) {
  return __uint_as_float(((unsigned int)(unsigned short)s) << 16);
}
__device__ inline float tanh_fast(float x) {
  float ax = fabsf(x);
  float e = __expf(-2.f * ax);
  float r = (1.f - e) / (1.f + e);
  return copysignf(r, x);
}

// ---------- K0: detect input dtype (bf16 vs f32) ----------
__global__ void k_detect(const unsigned int* embw, int* flagp) {
  __shared__ float red[256];
  int t = threadIdx.x;
  float mx = 0.f;
  for (int i = t; i < 1024; i += 256) {
    unsigned int w = embw[i];
    unsigned int fb = (w & 0xffffu) << 16;
    float a = fabsf(__uint_as_float(fb));
    if (!(a < 1e9f)) a = 1e9f;
    mx = fmaxf(mx, a);
  }
  red[t] = mx;
  __syncthreads();
  for (int s = 128; s > 0; s >>= 1) {
    if (t < s) red[t] = fmaxf(red[t], red[t + s]);
    __syncthreads();
  }
  if (t == 0) flagp[0] = (red[0] < 1000.f) ? 1 : 0;
}

// ---------- K1: relaT[d*64+r] = rela[r,d] ----------
__global__ void k_relat(const void* rela, float* relaT, const int* flagp) {
  int flag = flagp[0];
  int r = blockIdx.x;
  int d = threadIdx.x;
  relaT[d * NR + r] = cvt(rela, r * ND + d, flag);
}

// ---------- K1b: small params -> f32: sp[0..255]=b1, [256..511]=w2,
//                 [512..767]=out_w, [768]=b2, [769]=out_b ----------
__global__ void k_small(const void* b1, const void* w2, const void* outw,
                        const void* b2, const void* outb, float* sp,
                        const int* flagp) {
  int flag = flagp[0];
  int t = threadIdx.x;  // 256
  sp[t] = cvt(b1, t, flag);
  sp[256 + t] = cvt(w2, t, flag);
  sp[512 + t] = cvt(outw, t, flag);
  if (t == 0) {
    sp[768] = cvt(b2, 0, flag);
    sp[769] = cvt(outb, 0, flag);
  }
}

// ---------- K1c: pack att_w1 -> bf16 fragment order ----------
// flat = ((nt*8 + kstep)*64 + lane)*8 + i holds W1[k][n],
//   k = kstep*32 + (lane>>4)*8 + i, n = nt*16 + (lane&15)
__global__ void k_prepw(const void* w1, __hip_bfloat16* w1b, const int* flagp) {
  int flag = flagp[0];
  int flat = blockIdx.x * 256 + threadIdx.x;  // 65536
  int i = flat & 7;
  int lane = (flat >> 3) & 63;
  int kst = (flat >> 9) & 7;
  int nt = flat >> 12;
  int k = kst * 32 + (lane >> 4) * 8 + i;
  int n = nt * 16 + (lane & 15);
  w1b[flat] = __float2bfloat16(cvt(w1, k * ND + n, flag));
}

// ---------- K2: gather ----------
__global__ void k_gather(const int* head, const int* tail, const void* emb,
                         float* Af, float* Bf, const int* flagp) {
  int flag = flagp[0];
  int row = blockIdx.x;
  int t = threadIdx.x;
  if (row < NB * NW) {
    int ix = head[row];
    Af[row * ND + t] = cvt(emb, ix * ND + t, flag);
  } else {
    int rr = row - NB * NW;
    int ix = tail[rr];
    Bf[rr * ND + t] = cvt(emb, ix * ND + t, flag);
  }
}

// ---------- K3: Ah = A@Wa + fc_b, Bh = B@Wb, RW = rela@Wc ----------
__global__ void k_premm(const float* Af, const float* Bf, const void* rela,
                        const void* fcw, const void* fcb,
                        float* Ah, float* Bh, float* RW, const int* flagp) {
  int flag = flagp[0];
  int row = blockIdx.x;    // 2112
  int t = threadIdx.x;     // 256
  __shared__ float rl[ND];
  float* dst;
  int wbase, addb = 0;
  if (row < 1024) {
    rl[t] = Af[row * ND + t];
    wbase = 0; dst = Ah + row * ND; addb = 1;
  } else if (row < 2048) {
    int rr = row - 1024;
    rl[t] = Bf[rr * ND + t];
    wbase = ND; dst = Bh + rr * ND;
  } else {
    int rr = row - 2048;
    rl[t] = cvt(rela, rr * ND + t, flag);
    wbase = 2 * ND; dst = RW + rr * ND;
  }
  __syncthreads();
  float acc = 0.f;
  for (int k = 0; k < ND; ++k)
    acc += rl[k] * cvt(fcw, (wbase + k) * ND + t, flag);
  if (addb) acc += cvt(fcb, t, flag);
  dst[t] = acc;
}

// ---------- K4: scores -> mask -> softmax -> norm_scores ----------
__global__ void k_scores(const float* Af, const float* Bf, const float* relaT,
                         float* nsw, void* out, const int* flagp) {
  int flag = flagp[0];
  int bi = blockIdx.x;         // 1024
  int b = bi >> 6;
  int t = threadIdx.x;         // 256
  int r = t & 63;
  int q = t >> 6;
  __shared__ float Al[ND];
  __shared__ float Bl[ND];
  __shared__ float part[256];
  Al[t] = Af[bi * ND + t];
  __syncthreads();
  float preR[64];
#pragma unroll
  for (int i2 = 0; i2 < 64; ++i2) {
    int d = q * 64 + i2;
    preR[i2] = Al[d] * relaT[d * NR + r];
  }
  for (int j = 0; j < NV; ++j) {
    Bl[t] = Bf[(b * NV + j) * ND + t];
    __syncthreads();
    float acc = 0.f;
#pragma unroll
    for (int i2 = 0; i2 < 64; ++i2)
      acc += preR[i2] * Bl[q * 64 + i2];
    part[t] = acc;
    __syncthreads();
    if (t < 64) {
      float s = part[t] + part[64 + t] + part[128 + t] + part[192 + t];
      float nullv = __shfl(s, 63, 64);
      float m = (s <= nullv) ? NEGV : s;
      float mx = m;
#pragma unroll
      for (int o = 32; o > 0; o >>= 1) mx = fmaxf(mx, __shfl_xor(mx, o, 64));
      float e = __expf(m - mx);
      float sum = e;
#pragma unroll
      for (int o = 32; o > 0; o >>= 1) sum += __shfl_xor(sum, o, 64);
      float ns = e / sum;
      int nidx = (bi * 64 + j) * 64 + t;
      nsw[nidx] = ns;
      stv(out, 16 + NB * NN + nidx, ns, flag);
    }
    __syncthreads();
  }
}

// ---------- K5: tuple_vec = tanh(Ah + Bh + ns@RW) -> bf16 ----------
__global__ void k_tuple(const float* Ah, const float* Bh, const float* RW,
                        const float* nsw, __hip_bfloat16* tup) {
  int bi = blockIdx.x;       // 1024
  int b = bi >> 6;
  int t = threadIdx.x;       // 256
  __shared__ float nsl[NR];
  float RWc[64];
#pragma unroll
  for (int r = 0; r < 64; ++r) RWc[r] = RW[r * ND + t];
  float base0 = Ah[bi * ND + t];
  for (int j = 0; j < NV; ++j) {
    if (t < 64) nsl[t] = nsw[(bi * 64 + j) * 64 + t];
    __syncthreads();
    float acc = base0 + Bh[(b * NV + j) * ND + t];
#pragma unroll
    for (int r = 0; r < 64; ++r) acc += nsl[r] * RWc[r];
    tup[(bi * 64 + j) * ND + t] = __float2bfloat16(tanh_fast(acc));
    __syncthreads();
  }
}

// ---------- K6 (MFMA): att_raw = tanh(T@W1+b1)@w2+b2 ; dotv = T@out_w ----------
// T: 65536 x 256 bf16. Block = 64 rows (4 waves x 16-row M-tiles), N=256 full.
__global__ void __launch_bounds__(256) k_att2(const __hip_bfloat16* tup,
                                              const __hip_bfloat16* w1b,
                                              const float* sp,
                                              float* att_raw, float* dotv) {
  int t = threadIdx.x;
  int wv = t >> 6, lane = t & 63;
  int r0 = blockIdx.x * 64 + wv * 16;
  const short* tupS = (const short*)tup;
  const short* w1S = (const short*)w1b;
  const float* b1f = sp;
  const float* w2f = sp + 256;
  const float* owf = sp + 512;
  float b2v = sp[768];

  f32x4 acc[16];
#pragma unroll
  for (int i = 0; i < 16; ++i) acc[i] = (f32x4){0.f, 0.f, 0.f, 0.f};
  float dp = 0.f;
  int arow = r0 + (lane & 15);
  int kgrp = lane >> 4;

#pragma unroll
  for (int ks = 0; ks < 8; ++ks) {
    int k0 = ks * 32 + kgrp * 8;
    short8 a = *(const short8*)(tupS + (size_t)arow * ND + k0);
#pragma unroll
    for (int i = 0; i < 8; ++i)
      dp += bf2f(a[i]) * owf[k0 + i];
#pragma unroll
    for (int nt = 0; nt < 16; ++nt) {
      short8 bfr = *(const short8*)(w1S + (((nt * 8 + ks) * 64 + lane) << 3));
      acc[nt] = __builtin_amdgcn_mfma_f32_16x16x32_bf16(a, bfr, acc[nt], 0, 0, 0);
    }
  }

  // dotv: combine the 4 k-groups (lanes differing in bits 4,5)
  dp += __shfl_xor(dp, 16, 64);
  dp += __shfl_xor(dp, 32, 64);
  if (lane < 16) dotv[r0 + lane] = dp;

  // epilogue: C layout row=(lane>>4)*4+reg, col=nt*16+(lane&15)
  float part[4] = {0.f, 0.f, 0.f, 0.f};
#pragma unroll
  for (int nt = 0; nt < 16; ++nt) {
    int col = nt * 16 + (lane & 15);
    float b1v = b1f[col];
    float w2v = w2f[col];
#pragma unroll
    for (int reg = 0; reg < 4; ++reg) {
      float h = tanh_fast(acc[nt][reg] + b1v);
      part[reg] += h * w2v;
    }
  }
#pragma unroll
  for (int o = 1; o < 16; o <<= 1) {
#pragma unroll
    for (int reg = 0; reg < 4; ++reg)
      part[reg] += __shfl_xor(part[reg], o, 64);
  }
  if ((lane & 15) == 0) {
    int rb = r0 + (lane >> 4) * 4;
#pragma unroll
    for (int reg = 0; reg < 4; ++reg)
      att_raw[rb + reg] = part[reg] + b2v;
  }
}

// ---------- K7: att softmax over N -> att_norms out; logits ----------
__global__ void k_fuse(const float* att_raw, const float* dotv,
                       const float* sp, void* out, const int* flagp) {
  int flag = flagp[0];
  int b = blockIdx.x;
  int t = threadIdx.x;
  __shared__ float red[256];
  float vals[16];
  float mx = -3.4e38f;
#pragma unroll
  for (int c = 0; c < 16; ++c) {
    vals[c] = att_raw[b * NN + c * 256 + t];
    mx = fmaxf(mx, vals[c]);
  }
  red[t] = mx;
  __syncthreads();
  for (int s = 128; s > 0; s >>= 1) {
    if (t < s) red[t] = fmaxf(red[t], red[t + s]);
    __syncthreads();
  }
  float M = red[0];
  __syncthreads();
  float sm = 0.f;
#pragma unroll
  for (int c = 0; c < 16; ++c) {
    vals[c] = __expf(vals[c] - M);
    sm += vals[c];
  }
  red[t] = sm;
  __syncthreads();
  for (int s = 128; s > 0; s >>= 1) {
    if (t < s) red[t] += red[t + s];
    __syncthreads();
  }
  float Z = red[0];
  __syncthreads();
  float acc = 0.f;
#pragma unroll
  for (int c = 0; c < 16; ++c) {
    int n = c * 256 + t;
    float a = vals[c] / Z;
    stv(out, 16 + b * NN + n, a, flag);
    acc += a * dotv[b * NN + n];
  }
  red[t] = acc;
  __syncthreads();
  for (int s = 128; s > 0; s >>= 1) {
    if (t < s) red[t] += red[t + s];
    __syncthreads();
  }
  if (t == 0) stv(out, b, red[0] + sp[769], flag);   // + out_b
}

// ---------- host ----------
extern "C" void kernel_launch(void* const* d_in, const int* in_sizes, int n_in,
                              void* d_out, int out_size, void* d_ws, size_t ws_size,
                              hipStream_t stream) {
  const int* head = (const int*)d_in[0];
  const int* tail = (const int*)d_in[1];
  const void* emb = d_in[2];
  const void* rela = d_in[3];
  const void* fcw = d_in[4];
  const void* fcb = d_in[5];
  const void* w1 = d_in[6];
  const void* b1 = d_in[7];
  const void* w2 = d_in[8];
  const void* b2 = d_in[9];
  const void* outw = d_in[10];
  const void* outb = d_in[11];

  float* ws = (float*)d_ws;
  int* flagp = (int*)d_ws;
  const size_t O_RELAT = 16;
  const size_t O_AF = O_RELAT + 16384;
  const size_t O_BF = O_AF + 262144;
  const size_t O_AH = O_BF + 262144;
  const size_t O_BH = O_AH + 262144;
  const size_t O_RW = O_BH + 262144;
  const size_t O_NS = O_RW + 16384;
  const size_t O_ATTR = O_NS + 4194304;
  const size_t O_DOT = O_ATTR + 65536;
  const size_t O_SP = O_DOT + 65536;
  const size_t O_W1B = O_SP + 1024;     // 65536 bf16
  const size_t O_TUP = O_W1B + 32768;   // 16.8M bf16

  float* relaT = ws + O_RELAT;
  float* Af = ws + O_AF;
  float* Bf = ws + O_BF;
  float* Ah = ws + O_AH;
  float* Bh = ws + O_BH;
  float* RW = ws + O_RW;
  float* nsw = ws + O_NS;
  float* attr = ws + O_ATTR;
  float* dotv = ws + O_DOT;
  float* sp = ws + O_SP;
  __hip_bfloat16* w1b = (__hip_bfloat16*)(ws + O_W1B);
  __hip_bfloat16* tup = (__hip_bfloat16*)(ws + O_TUP);

  hipLaunchKernelGGL(k_detect, dim3(1), dim3(256), 0, stream,
                     (const unsigned int*)emb, flagp);
  hipLaunchKernelGGL(k_relat, dim3(64), dim3(256), 0, stream, rela, relaT, flagp);
  hipLaunchKernelGGL(k_small, dim3(1), dim3(256), 0, stream,
                     b1, w2, outw, b2, outb, sp, flagp);
  hipLaunchKernelGGL(k_prepw, dim3(256), dim3(256), 0, stream, w1, w1b, flagp);
  hipLaunchKernelGGL(k_gather, dim3(2048), dim3(256), 0, stream,
                     head, tail, emb, Af, Bf, flagp);
  hipLaunchKernelGGL(k_premm, dim3(2112), dim3(256), 0, stream,
                     Af, Bf, rela, fcw, fcb, Ah, Bh, RW, flagp);
  hipLaunchKernelGGL(k_scores, dim3(1024), dim3(256), 0, stream,
                     Af, Bf, relaT, nsw, d_out, flagp);
  hipLaunchKernelGGL(k_tuple, dim3(1024), dim3(256), 0, stream,
                     Ah, Bh, RW, nsw, tup);
  hipLaunchKernelGGL(k_att2, dim3(1024), dim3(256), 0, stream,
                     tup, w1b, sp, attr, dotv);
  hipLaunchKernelGGL(k_fuse, dim3(16), dim3(256), 0, stream,
                     attr, dotv, sp, d_out, flagp);
}

// Round 4
// 288.214 us; speedup vs baseline: 3.8803x; 1.3006x over previous
//
#include <hip/hip_runtime.h>
#include <hip/hip_bf16.h>

#define NB 16
#define NW 64
#define NV 64
#define ND 256
#define NR 64
#define NN 4096
#define NEGV -10000000000.0f

typedef __attribute__((ext_vector_type(8))) short short8;
typedef __attribute__((ext_vector_type(4))) float f32x4;

__device__ inline float cvt(const void* p, int idx, int flag) {
  if (flag) return __bfloat162float(((const __hip_bfloat16*)p)[idx]);
  return ((const float*)p)[idx];
}
__device__ inline void stv(void* p, int idx, float v, int flag) {
  if (flag) ((__hip_bfloat16*)p)[idx] = __float2bfloat16(v);
  else ((float*)p)[idx] = v;
}
__device__ inline float bf2f(short s) {
  return __uint_as_float(((unsigned int)(unsigned short)s) << 16);
}
__device__ inline float tanh_fast(float x) {
  float ax = fabsf(x);
  float e = __expf(-2.f * ax);
  float r = (1.f - e) / (1.f + e);
  return copysignf(r, x);
}

// ---------- K0: detect input dtype (bf16 vs f32) ----------
__global__ void k_detect(const unsigned int* embw, int* flagp) {
  __shared__ float red[256];
  int t = threadIdx.x;
  float mx = 0.f;
  for (int i = t; i < 1024; i += 256) {
    unsigned int w = embw[i];
    unsigned int fb = (w & 0xffffu) << 16;
    float a = fabsf(__uint_as_float(fb));
    if (!(a < 1e9f)) a = 1e9f;
    mx = fmaxf(mx, a);
  }
  red[t] = mx;
  __syncthreads();
  for (int s = 128; s > 0; s >>= 1) {
    if (t < s) red[t] = fmaxf(red[t], red[t + s]);
    __syncthreads();
  }
  if (t == 0) flagp[0] = (red[0] < 1000.f) ? 1 : 0;
}

// ---------- K1 (merged prep): relaT | small params | w1 pack | gather ----------
// blocks [0,64): relaT[d*64+r] = rela[r,d]
// block 64:      sp[0..255]=b1, [256..511]=w2, [512..767]=out_w, [768]=b2, [769]=out_b
// blocks [65,321): pack att_w1 -> bf16 MFMA fragment order
// blocks [321,2369): gather A = emb[head], B = emb[tail]
__global__ void k_prep(const void* rela, float* relaT,
                       const void* b1, const void* w2, const void* outw,
                       const void* b2, const void* outb, float* sp,
                       const void* w1, __hip_bfloat16* w1b,
                       const int* head, const int* tail, const void* emb,
                       float* Af, float* Bf, const int* flagp) {
  int flag = flagp[0];
  int blk = blockIdx.x;
  int t = threadIdx.x;
  if (blk < 64) {
    relaT[t * NR + blk] = cvt(rela, blk * ND + t, flag);
  } else if (blk == 64) {
    sp[t] = cvt(b1, t, flag);
    sp[256 + t] = cvt(w2, t, flag);
    sp[512 + t] = cvt(outw, t, flag);
    if (t == 0) {
      sp[768] = cvt(b2, 0, flag);
      sp[769] = cvt(outb, 0, flag);
    }
  } else if (blk < 321) {
    int flat = (blk - 65) * 256 + t;  // 65536
    int i = flat & 7;
    int lane = (flat >> 3) & 63;
    int kst = (flat >> 9) & 7;
    int nt = flat >> 12;
    int k = kst * 32 + (lane >> 4) * 8 + i;
    int n = nt * 16 + (lane & 15);
    w1b[flat] = __float2bfloat16(cvt(w1, k * ND + n, flag));
  } else {
    int row = blk - 321;  // 0..2047
    if (row < NB * NW) {
      int ix = head[row];
      Af[row * ND + t] = cvt(emb, ix * ND + t, flag);
    } else {
      int rr = row - NB * NW;
      int ix = tail[rr];
      Bf[rr * ND + t] = cvt(emb, ix * ND + t, flag);
    }
  }
}

// ---------- K3: Ah = A@Wa + fc_b, Bh = B@Wb, RW = rela@Wc ----------
__global__ void k_premm(const float* Af, const float* Bf, const void* rela,
                        const void* fcw, const void* fcb,
                        float* Ah, float* Bh, float* RW, const int* flagp) {
  int flag = flagp[0];
  int row = blockIdx.x;    // 2112
  int t = threadIdx.x;     // 256
  __shared__ float rl[ND];
  float* dst;
  int wbase, addb = 0;
  if (row < 1024) {
    rl[t] = Af[row * ND + t];
    wbase = 0; dst = Ah + row * ND; addb = 1;
  } else if (row < 2048) {
    int rr = row - 1024;
    rl[t] = Bf[rr * ND + t];
    wbase = ND; dst = Bh + rr * ND;
  } else {
    int rr = row - 2048;
    rl[t] = cvt(rela, rr * ND + t, flag);
    wbase = 2 * ND; dst = RW + rr * ND;
  }
  __syncthreads();
  float a0 = 0.f, a1 = 0.f, a2 = 0.f, a3 = 0.f;
  for (int k = 0; k < ND; k += 4) {
    a0 += rl[k]     * cvt(fcw, (wbase + k) * ND + t, flag);
    a1 += rl[k + 1] * cvt(fcw, (wbase + k + 1) * ND + t, flag);
    a2 += rl[k + 2] * cvt(fcw, (wbase + k + 2) * ND + t, flag);
    a3 += rl[k + 3] * cvt(fcw, (wbase + k + 3) * ND + t, flag);
  }
  float acc = (a0 + a1) + (a2 + a3);
  if (addb) acc += cvt(fcb, t, flag);
  dst[t] = acc;
}

// ---------- K4: scores -> mask -> softmax -> norm_scores (batch-4 j) ----------
// Block = (b,i). Per iteration: 4 j's; wave w owns softmax of j = jg*4 + w.
// Score arithmetic is bit-identical to the original (same chunk order, same
// 4-way partial-sum order) — required for the s<=null mask comparison.
__global__ void __launch_bounds__(256) k_scores(const float* Af, const float* Bf,
                                                const float* relaT, void* out,
                                                const int* flagp) {
  int flag = flagp[0];
  int bi = blockIdx.x;         // 1024 = b*64 + i
  int b = bi >> 6;
  int t = threadIdx.x;         // 256
  int r = t & 63;
  int q = t >> 6;
  __shared__ float Al[ND];
  __shared__ float Bl[4 * ND];
  __shared__ float part[4 * 256];
  Al[t] = Af[bi * ND + t];
  __syncthreads();
  float preR[64];
#pragma unroll
  for (int i2 = 0; i2 < 64; ++i2) {
    int d = q * 64 + i2;
    preR[i2] = Al[d] * relaT[d * NR + r];
  }
  for (int jg = 0; jg < 16; ++jg) {
#pragma unroll
    for (int jj = 0; jj < 4; ++jj)
      Bl[jj * ND + t] = Bf[(b * NV + jg * 4 + jj) * ND + t];
    __syncthreads();
#pragma unroll
    for (int jj = 0; jj < 4; ++jj) {
      float acc = 0.f;
#pragma unroll
      for (int i2 = 0; i2 < 64; ++i2)
        acc += preR[i2] * Bl[jj * ND + q * 64 + i2];
      part[jj * 256 + t] = acc;
    }
    __syncthreads();
    {
      int j4 = q;   // this wave's j
      float s = part[j4 * 256 + r] + part[j4 * 256 + 64 + r]
              + part[j4 * 256 + 128 + r] + part[j4 * 256 + 192 + r];
      float nullv = __shfl(s, 63, 64);
      float m = (s <= nullv) ? NEGV : s;
      float mx = m;
#pragma unroll
      for (int o = 32; o > 0; o >>= 1) mx = fmaxf(mx, __shfl_xor(mx, o, 64));
      float e = __expf(m - mx);
      float sum = e;
#pragma unroll
      for (int o = 32; o > 0; o >>= 1) sum += __shfl_xor(sum, o, 64);
      float ns = e / sum;
      int j = jg * 4 + j4;
      int nidx = (bi * 64 + j) * 64 + r;
      stv(out, 16 + NB * NN + nidx, ns, flag);
    }
    __syncthreads();
  }
}

// ---------- K5: tuple_vec = tanh(Ah + Bh + ns@RW) -> bf16 (batch-4 j) ----------
// Reads norm_scores back from d_out (bf16/f32 per flag).
__global__ void __launch_bounds__(256) k_tuple(const float* Ah, const float* Bh,
                                               const float* RW, const void* out,
                                               __hip_bfloat16* tup,
                                               const int* flagp) {
  int flag = flagp[0];
  int bi = blockIdx.x;       // 1024
  int b = bi >> 6;
  int t = threadIdx.x;       // 256
  __shared__ float nsl[4][NR];
  float RWc[64];
#pragma unroll
  for (int rr = 0; rr < 64; ++rr) RWc[rr] = RW[rr * ND + t];
  float base0 = Ah[bi * ND + t];
  int nsbase = 16 + NB * NN + bi * 64 * 64;
  for (int jg = 0; jg < 16; ++jg) {
    nsl[t >> 6][t & 63] = cvt(out, nsbase + (jg * 4 + (t >> 6)) * 64 + (t & 63), flag);
    __syncthreads();
#pragma unroll
    for (int jj = 0; jj < 4; ++jj) {
      int j = jg * 4 + jj;
      float acc = base0 + Bh[(b * NV + j) * ND + t];
#pragma unroll
      for (int rr = 0; rr < 64; ++rr) acc += nsl[jj][rr] * RWc[rr];
      tup[((size_t)bi * 64 + j) * ND + t] = __float2bfloat16(tanh_fast(acc));
    }
    __syncthreads();
  }
}

// ---------- K6 (MFMA): att_raw = tanh(T@W1+b1)@w2+b2 ; dotv = T@out_w ----------
// Block = 128 rows (4 waves x 2 16-row M-tiles). Halves w1b L2 traffic per row.
__global__ void __launch_bounds__(256) k_att2(const __hip_bfloat16* tup,
                                              const __hip_bfloat16* w1b,
                                              const float* sp,
                                              float* att_raw, float* dotv) {
  int t = threadIdx.x;
  int wv = t >> 6, lane = t & 63;
  int r0 = blockIdx.x * 128 + wv * 32;
  const short* tupS = (const short*)tup;
  const short* w1S = (const short*)w1b;
  const float* owf = sp + 512;
  float b2v = sp[768];

  f32x4 acc0[16], acc1[16];
#pragma unroll
  for (int i = 0; i < 16; ++i) {
    acc0[i] = (f32x4){0.f, 0.f, 0.f, 0.f};
    acc1[i] = (f32x4){0.f, 0.f, 0.f, 0.f};
  }
  float dp0 = 0.f, dp1 = 0.f;
  int arow0 = r0 + (lane & 15);
  int arow1 = arow0 + 16;
  int kgrp = lane >> 4;

#pragma unroll
  for (int ks = 0; ks < 8; ++ks) {
    int k0 = ks * 32 + kgrp * 8;
    short8 a0 = *(const short8*)(tupS + (size_t)arow0 * ND + k0);
    short8 a1 = *(const short8*)(tupS + (size_t)arow1 * ND + k0);
#pragma unroll
    for (int i = 0; i < 8; ++i) {
      float w = owf[k0 + i];
      dp0 += bf2f(a0[i]) * w;
      dp1 += bf2f(a1[i]) * w;
    }
#pragma unroll
    for (int nt = 0; nt < 16; ++nt) {
      short8 bfr = *(const short8*)(w1S + (((nt * 8 + ks) * 64 + lane) << 3));
      acc0[nt] = __builtin_amdgcn_mfma_f32_16x16x32_bf16(a0, bfr, acc0[nt], 0, 0, 0);
      acc1[nt] = __builtin_amdgcn_mfma_f32_16x16x32_bf16(a1, bfr, acc1[nt], 0, 0, 0);
    }
  }

  dp0 += __shfl_xor(dp0, 16, 64); dp0 += __shfl_xor(dp0, 32, 64);
  dp1 += __shfl_xor(dp1, 16, 64); dp1 += __shfl_xor(dp1, 32, 64);
  if (lane < 16) {
    dotv[r0 + lane] = dp0;
    dotv[r0 + 16 + lane] = dp1;
  }

  float p0[4] = {0.f, 0.f, 0.f, 0.f};
  float p1[4] = {0.f, 0.f, 0.f, 0.f};
#pragma unroll
  for (int nt = 0; nt < 16; ++nt) {
    int col = nt * 16 + (lane & 15);
    float b1v = sp[col];
    float w2v = sp[256 + col];
#pragma unroll
    for (int reg = 0; reg < 4; ++reg) {
      p0[reg] += tanh_fast(acc0[nt][reg] + b1v) * w2v;
      p1[reg] += tanh_fast(acc1[nt][reg] + b1v) * w2v;
    }
  }
#pragma unroll
  for (int o = 1; o < 16; o <<= 1) {
#pragma unroll
    for (int reg = 0; reg < 4; ++reg) {
      p0[reg] += __shfl_xor(p0[reg], o, 64);
      p1[reg] += __shfl_xor(p1[reg], o, 64);
    }
  }
  if ((lane & 15) == 0) {
    int rb = r0 + (lane >> 4) * 4;
#pragma unroll
    for (int reg = 0; reg < 4; ++reg) {
      att_raw[rb + reg] = p0[reg] + b2v;
      att_raw[rb + 16 + reg] = p1[reg] + b2v;
    }
  }
}

// ---------- K7: att softmax over N -> att_norms out; logits ----------
__global__ void k_fuse(const float* att_raw, const float* dotv,
                       const float* sp, void* out, const int* flagp) {
  int flag = flagp[0];
  int b = blockIdx.x;
  int t = threadIdx.x;
  __shared__ float red[256];
  float vals[16];
  float mx = -3.4e38f;
#pragma unroll
  for (int c = 0; c < 16; ++c) {
    vals[c] = att_raw[b * NN + c * 256 + t];
    mx = fmaxf(mx, vals[c]);
  }
  red[t] = mx;
  __syncthreads();
  for (int s = 128; s > 0; s >>= 1) {
    if (t < s) red[t] = fmaxf(red[t], red[t + s]);
    __syncthreads();
  }
  float M = red[0];
  __syncthreads();
  float sm = 0.f;
#pragma unroll
  for (int c = 0; c < 16; ++c) {
    vals[c] = __expf(vals[c] - M);
    sm += vals[c];
  }
  red[t] = sm;
  __syncthreads();
  for (int s = 128; s > 0; s >>= 1) {
    if (t < s) red[t] += red[t + s];
    __syncthreads();
  }
  float Z = red[0];
  __syncthreads();
  float acc = 0.f;
#pragma unroll
  for (int c = 0; c < 16; ++c) {
    int n = c * 256 + t;
    float a = vals[c] / Z;
    stv(out, 16 + b * NN + n, a, flag);
    acc += a * dotv[b * NN + n];
  }
  red[t] = acc;
  __syncthreads();
  for (int s = 128; s > 0; s >>= 1) {
    if (t < s) red[t] += red[t + s];
    __syncthreads();
  }
  if (t == 0) stv(out, b, red[0] + sp[769], flag);   // + out_b
}

// ---------- host ----------
extern "C" void kernel_launch(void* const* d_in, const int* in_sizes, int n_in,
                              void* d_out, int out_size, void* d_ws, size_t ws_size,
                              hipStream_t stream) {
  const int* head = (const int*)d_in[0];
  const int* tail = (const int*)d_in[1];
  const void* emb = d_in[2];
  const void* rela = d_in[3];
  const void* fcw = d_in[4];
  const void* fcb = d_in[5];
  const void* w1 = d_in[6];
  const void* b1 = d_in[7];
  const void* w2 = d_in[8];
  const void* b2 = d_in[9];
  const void* outw = d_in[10];
  const void* outb = d_in[11];

  float* ws = (float*)d_ws;
  int* flagp = (int*)d_ws;
  const size_t O_RELAT = 16;
  const size_t O_AF = O_RELAT + 16384;
  const size_t O_BF = O_AF + 262144;
  const size_t O_AH = O_BF + 262144;
  const size_t O_BH = O_AH + 262144;
  const size_t O_RW = O_BH + 262144;
  const size_t O_ATTR = O_RW + 16384;
  const size_t O_DOT = O_ATTR + 65536;
  const size_t O_SP = O_DOT + 65536;
  const size_t O_W1B = O_SP + 1024;     // 65536 bf16
  const size_t O_TUP = O_W1B + 32768;   // 16.8M bf16

  float* relaT = ws + O_RELAT;
  float* Af = ws + O_AF;
  float* Bf = ws + O_BF;
  float* Ah = ws + O_AH;
  float* Bh = ws + O_BH;
  float* RW = ws + O_RW;
  float* attr = ws + O_ATTR;
  float* dotv = ws + O_DOT;
  float* sp = ws + O_SP;
  __hip_bfloat16* w1b = (__hip_bfloat16*)(ws + O_W1B);
  __hip_bfloat16* tup = (__hip_bfloat16*)(ws + O_TUP);

  hipLaunchKernelGGL(k_detect, dim3(1), dim3(256), 0, stream,
                     (const unsigned int*)emb, flagp);
  hipLaunchKernelGGL(k_prep, dim3(2369), dim3(256), 0, stream,
                     rela, relaT, b1, w2, outw, b2, outb, sp,
                     w1, w1b, head, tail, emb, Af, Bf, flagp);
  hipLaunchKernelGGL(k_premm, dim3(2112), dim3(256), 0, stream,
                     Af, Bf, rela, fcw, fcb, Ah, Bh, RW, flagp);
  hipLaunchKernelGGL(k_scores, dim3(1024), dim3(256), 0, stream,
                     Af, Bf, relaT, d_out, flagp);
  hipLaunchKernelGGL(k_tuple, dim3(1024), dim3(256), 0, stream,
                     Ah, Bh, RW, d_out, tup, flagp);
  hipLaunchKernelGGL(k_att2, dim3(512), dim3(256), 0, stream,
                     tup, w1b, sp, attr, dotv);
  hipLaunchKernelGGL(k_fuse, dim3(16), dim3(256), 0, stream,
                     attr, dotv, sp, d_out, flagp);
}

// Round 5
// 265.152 us; speedup vs baseline: 4.2178x; 1.0870x over previous
//
#include <hip/hip_runtime.h>
#include <hip/hip_bf16.h>

#define NB 16
#define NW 64
#define NV 64
#define ND 256
#define NR 64
#define NN 4096
#define NEGV -10000000000.0f

typedef __attribute__((ext_vector_type(8))) short short8;
typedef __attribute__((ext_vector_type(4))) float f32x4;

__device__ inline float cvt(const void* p, int idx, int flag) {
  if (flag) return __bfloat162float(((const __hip_bfloat16*)p)[idx]);
  return ((const float*)p)[idx];
}
__device__ inline void stv(void* p, int idx, float v, int flag) {
  if (flag) ((__hip_bfloat16*)p)[idx] = __float2bfloat16(v);
  else ((float*)p)[idx] = v;
}
__device__ inline float bf2f(short s) {
  return __uint_as_float(((unsigned int)(unsigned short)s) << 16);
}
__device__ inline float tanh_fast(float x) {
  float ax = fabsf(x);
  float e = __expf(-2.f * ax);
  float r = (1.f - e) / (1.f + e);
  return copysignf(r, x);
}

// ---------- K0: detect input dtype (bf16 vs f32) ----------
__global__ void k_detect(const unsigned int* embw, int* flagp) {
  __shared__ float red[256];
  int t = threadIdx.x;
  float mx = 0.f;
  for (int i = t; i < 1024; i += 256) {
    unsigned int w = embw[i];
    unsigned int fb = (w & 0xffffu) << 16;
    float a = fabsf(__uint_as_float(fb));
    if (!(a < 1e9f)) a = 1e9f;
    mx = fmaxf(mx, a);
  }
  red[t] = mx;
  __syncthreads();
  for (int s = 128; s > 0; s >>= 1) {
    if (t < s) red[t] = fmaxf(red[t], red[t + s]);
    __syncthreads();
  }
  if (t == 0) flagp[0] = (red[0] < 1000.f) ? 1 : 0;
}

// ---------- K1 (merged prep): relaT | small params | w1 pack | gather ----------
__global__ void k_prep(const void* rela, float* relaT,
                       const void* b1, const void* w2, const void* outw,
                       const void* b2, const void* outb, float* sp,
                       const void* w1, __hip_bfloat16* w1b,
                       const int* head, const int* tail, const void* emb,
                       float* Af, float* Bf, const int* flagp) {
  int flag = flagp[0];
  int blk = blockIdx.x;
  int t = threadIdx.x;
  if (blk < 64) {
    relaT[t * NR + blk] = cvt(rela, blk * ND + t, flag);
  } else if (blk == 64) {
    sp[t] = cvt(b1, t, flag);
    sp[256 + t] = cvt(w2, t, flag);
    sp[512 + t] = cvt(outw, t, flag);
    if (t == 0) {
      sp[768] = cvt(b2, 0, flag);
      sp[769] = cvt(outb, 0, flag);
    }
  } else if (blk < 321) {
    int flat = (blk - 65) * 256 + t;  // 65536
    int i = flat & 7;
    int lane = (flat >> 3) & 63;
    int kst = (flat >> 9) & 7;
    int nt = flat >> 12;
    int k = kst * 32 + (lane >> 4) * 8 + i;
    int n = nt * 16 + (lane & 15);
    w1b[flat] = __float2bfloat16(cvt(w1, k * ND + n, flag));
  } else {
    int row = blk - 321;  // 0..2047
    if (row < NB * NW) {
      int ix = head[row];
      Af[row * ND + t] = cvt(emb, ix * ND + t, flag);
    } else {
      int rr = row - NB * NW;
      int ix = tail[rr];
      Bf[rr * ND + t] = cvt(emb, ix * ND + t, flag);
    }
  }
}

// ---------- K3: Ah = A@Wa + fc_b, Bh = B@Wb, RWb = pack(rela@Wc) ----------
// 4 rows per block: 528 blocks = 256 (A) + 256 (B) + 16 (rela).
__global__ void __launch_bounds__(256) k_premm(const float* Af, const float* Bf,
                                               const void* rela, const void* fcw,
                                               const void* fcb, float* Ah,
                                               float* Bh, __hip_bfloat16* rwb,
                                               const int* flagp) {
  int flag = flagp[0];
  int blk = blockIdx.x;
  int t = threadIdx.x;
  __shared__ float rl[4][ND];
  int base, wbase, addb = 0, isr = 0;
  const float* src = Af;
  if (blk < 256) { base = blk * 4; wbase = 0; addb = 1; }
  else if (blk < 512) { base = (blk - 256) * 4; src = Bf; wbase = ND; }
  else { base = (blk - 512) * 4; wbase = 2 * ND; isr = 1; }
#pragma unroll
  for (int i = 0; i < 4; ++i)
    rl[i][t] = isr ? cvt(rela, (base + i) * ND + t, flag)
                   : src[(base + i) * ND + t];
  __syncthreads();
  float acc0 = 0.f, acc1 = 0.f, acc2 = 0.f, acc3 = 0.f;
  const f32x4* r0p = (const f32x4*)rl[0];
  const f32x4* r1p = (const f32x4*)rl[1];
  const f32x4* r2p = (const f32x4*)rl[2];
  const f32x4* r3p = (const f32x4*)rl[3];
  for (int k4 = 0; k4 < 64; ++k4) {
    float w0 = cvt(fcw, (wbase + k4 * 4 + 0) * ND + t, flag);
    float w1v = cvt(fcw, (wbase + k4 * 4 + 1) * ND + t, flag);
    float w2v = cvt(fcw, (wbase + k4 * 4 + 2) * ND + t, flag);
    float w3v = cvt(fcw, (wbase + k4 * 4 + 3) * ND + t, flag);
    f32x4 r0 = r0p[k4], r1 = r1p[k4], r2 = r2p[k4], r3 = r3p[k4];
    acc0 += r0.x * w0 + r0.y * w1v + r0.z * w2v + r0.w * w3v;
    acc1 += r1.x * w0 + r1.y * w1v + r1.z * w2v + r1.w * w3v;
    acc2 += r2.x * w0 + r2.y * w1v + r2.z * w2v + r2.w * w3v;
    acc3 += r3.x * w0 + r3.y * w1v + r3.z * w2v + r3.w * w3v;
  }
  float bias = addb ? cvt(fcb, t, flag) : 0.f;
  float res[4] = {acc0 + bias, acc1 + bias, acc2 + bias, acc3 + bias};
  if (!isr) {
    float* dst = addb ? Ah : Bh;
#pragma unroll
    for (int i = 0; i < 4; ++i) dst[(base + i) * ND + t] = res[i];
  } else {
    // pack RW[rr][t] into bf16 MFMA B-fragment order (K=64, N=256)
#pragma unroll
    for (int i = 0; i < 4; ++i) {
      int rr = base + i;
      int ks = rr >> 5, ii = rr & 7, lh = (rr >> 3) & 3;
      int nt = t >> 4, ll = t & 15;
      int flat = ((nt * 2 + ks) * 64 + lh * 16 + ll) * 8 + ii;
      rwb[flat] = __float2bfloat16(res[i]);
    }
  }
}

// ---------- K4: scores -> mask -> softmax -> norm_scores (batch-4 j) ----------
// Score arithmetic bit-identical to R3 (same FMA order) — mask s<=null is
// knife-edge, must stay f32. Writes ns to d_out AND bf16 nsb for k_tuple2.
__global__ void __launch_bounds__(256) k_scores(const float* Af, const float* Bf,
                                                const float* relaT, void* out,
                                                __hip_bfloat16* nsb,
                                                const int* flagp) {
  int flag = flagp[0];
  int bi = blockIdx.x;         // 1024 = b*64 + i
  int b = bi >> 6;
  int t = threadIdx.x;         // 256
  int r = t & 63;
  int q = t >> 6;
  __shared__ float Al[ND];
  __shared__ float Bl[4 * ND];
  __shared__ float part[4 * 256];
  Al[t] = Af[bi * ND + t];
  __syncthreads();
  float preR[64];
#pragma unroll
  for (int i2 = 0; i2 < 64; ++i2) {
    int d = q * 64 + i2;
    preR[i2] = Al[d] * relaT[d * NR + r];
  }
  const f32x4* Bl4 = (const f32x4*)Bl;
  for (int jg = 0; jg < 16; ++jg) {
#pragma unroll
    for (int jj = 0; jj < 4; ++jj)
      Bl[jj * ND + t] = Bf[(b * NV + jg * 4 + jj) * ND + t];
    __syncthreads();
#pragma unroll
    for (int jj = 0; jj < 4; ++jj) {
      float acc = 0.f;
      int ib = jj * 64 + q * 16;
#pragma unroll
      for (int i4 = 0; i4 < 16; ++i4) {
        f32x4 bv = Bl4[ib + i4];
        acc += preR[i4 * 4 + 0] * bv.x;
        acc += preR[i4 * 4 + 1] * bv.y;
        acc += preR[i4 * 4 + 2] * bv.z;
        acc += preR[i4 * 4 + 3] * bv.w;
      }
      part[jj * 256 + t] = acc;
    }
    __syncthreads();
    {
      int j4 = q;   // this wave's j
      float s = part[j4 * 256 + r] + part[j4 * 256 + 64 + r]
              + part[j4 * 256 + 128 + r] + part[j4 * 256 + 192 + r];
      float nullv = __shfl(s, 63, 64);
      float m = (s <= nullv) ? NEGV : s;
      float mx = m;
#pragma unroll
      for (int o = 32; o > 0; o >>= 1) mx = fmaxf(mx, __shfl_xor(mx, o, 64));
      float e = __expf(m - mx);
      float sum = e;
#pragma unroll
      for (int o = 32; o > 0; o >>= 1) sum += __shfl_xor(sum, o, 64);
      float ns = e / sum;
      int j = jg * 4 + j4;
      int nidx = (bi * 64 + j) * 64 + r;
      stv(out, 16 + NB * NN + nidx, ns, flag);
      nsb[nidx] = __float2bfloat16(ns);
    }
    __syncthreads();
  }
}

// ---------- K5 (MFMA): tuple = tanh(NS@RW + Ah + Bh) -> bf16 ----------
// Block = one bi (64 rows), 4 waves x 16-row M-tile, N=256, K=64.
__global__ void __launch_bounds__(256) k_tuple2(const __hip_bfloat16* nsb,
                                                const __hip_bfloat16* rwb,
                                                const float* Ah, const float* Bh,
                                                __hip_bfloat16* tup) {
  int t = threadIdx.x;
  int wv = t >> 6, lane = t & 63;
  int bi = blockIdx.x;       // 1024
  int b = bi >> 6;
  const short* nsS = (const short*)nsb;
  const short* rwS = (const short*)rwb;
  int m = lane & 15;
  int kgrp = lane >> 4;
  f32x4 acc[16];
#pragma unroll
  for (int i = 0; i < 16; ++i) acc[i] = (f32x4){0.f, 0.f, 0.f, 0.f};
  int nrow = bi * 64 + wv * 16 + m;
#pragma unroll
  for (int ks = 0; ks < 2; ++ks) {
    short8 a = *(const short8*)(nsS + (size_t)nrow * 64 + ks * 32 + kgrp * 8);
#pragma unroll
    for (int nt = 0; nt < 16; ++nt) {
      short8 bfr = *(const short8*)(rwS + (((nt * 2 + ks) * 64 + lane) << 3));
      acc[nt] = __builtin_amdgcn_mfma_f32_16x16x32_bf16(a, bfr, acc[nt], 0, 0, 0);
    }
  }
  // C layout: row=(lane>>4)*4+reg (tile-local), col=nt*16+m
  int rbase = bi * 64 + wv * 16 + (lane >> 4) * 4;
  int jbase = rbase & 63;
#pragma unroll
  for (int nt = 0; nt < 16; ++nt) {
    int col = nt * 16 + m;
    float ahv = Ah[bi * ND + col];
#pragma unroll
    for (int reg = 0; reg < 4; ++reg) {
      int ng = rbase + reg;
      float v = acc[nt][reg] + ahv + Bh[(size_t)(b * 64 + jbase + reg) * ND + col];
      tup[(size_t)ng * ND + col] = __float2bfloat16(tanh_fast(v));
    }
  }
}

// ---------- K6 (MFMA): att_raw = tanh(T@W1+b1)@w2+b2 ; dotv = T@out_w ----------
__global__ void __launch_bounds__(256) k_att2(const __hip_bfloat16* tup,
                                              const __hip_bfloat16* w1b,
                                              const float* sp,
                                              float* att_raw, float* dotv) {
  int t = threadIdx.x;
  int wv = t >> 6, lane = t & 63;
  int r0 = blockIdx.x * 128 + wv * 32;
  const short* tupS = (const short*)tup;
  const short* w1S = (const short*)w1b;
  const float* owf = sp + 512;
  float b2v = sp[768];

  f32x4 acc0[16], acc1[16];
#pragma unroll
  for (int i = 0; i < 16; ++i) {
    acc0[i] = (f32x4){0.f, 0.f, 0.f, 0.f};
    acc1[i] = (f32x4){0.f, 0.f, 0.f, 0.f};
  }
  float dp0 = 0.f, dp1 = 0.f;
  int arow0 = r0 + (lane & 15);
  int arow1 = arow0 + 16;
  int kgrp = lane >> 4;

#pragma unroll
  for (int ks = 0; ks < 8; ++ks) {
    int k0 = ks * 32 + kgrp * 8;
    short8 a0 = *(const short8*)(tupS + (size_t)arow0 * ND + k0);
    short8 a1 = *(const short8*)(tupS + (size_t)arow1 * ND + k0);
#pragma unroll
    for (int i = 0; i < 8; ++i) {
      float w = owf[k0 + i];
      dp0 += bf2f(a0[i]) * w;
      dp1 += bf2f(a1[i]) * w;
    }
#pragma unroll
    for (int nt = 0; nt < 16; ++nt) {
      short8 bfr = *(const short8*)(w1S + (((nt * 8 + ks) * 64 + lane) << 3));
      acc0[nt] = __builtin_amdgcn_mfma_f32_16x16x32_bf16(a0, bfr, acc0[nt], 0, 0, 0);
      acc1[nt] = __builtin_amdgcn_mfma_f32_16x16x32_bf16(a1, bfr, acc1[nt], 0, 0, 0);
    }
  }

  dp0 += __shfl_xor(dp0, 16, 64); dp0 += __shfl_xor(dp0, 32, 64);
  dp1 += __shfl_xor(dp1, 16, 64); dp1 += __shfl_xor(dp1, 32, 64);
  if (lane < 16) {
    dotv[r0 + lane] = dp0;
    dotv[r0 + 16 + lane] = dp1;
  }

  float p0[4] = {0.f, 0.f, 0.f, 0.f};
  float p1[4] = {0.f, 0.f, 0.f, 0.f};
#pragma unroll
  for (int nt = 0; nt < 16; ++nt) {
    int col = nt * 16 + (lane & 15);
    float b1v = sp[col];
    float w2v = sp[256 + col];
#pragma unroll
    for (int reg = 0; reg < 4; ++reg) {
      p0[reg] += tanh_fast(acc0[nt][reg] + b1v) * w2v;
      p1[reg] += tanh_fast(acc1[nt][reg] + b1v) * w2v;
    }
  }
#pragma unroll
  for (int o = 1; o < 16; o <<= 1) {
#pragma unroll
    for (int reg = 0; reg < 4; ++reg) {
      p0[reg] += __shfl_xor(p0[reg], o, 64);
      p1[reg] += __shfl_xor(p1[reg], o, 64);
    }
  }
  if ((lane & 15) == 0) {
    int rb = r0 + (lane >> 4) * 4;
#pragma unroll
    for (int reg = 0; reg < 4; ++reg) {
      att_raw[rb + reg] = p0[reg] + b2v;
      att_raw[rb + 16 + reg] = p1[reg] + b2v;
    }
  }
}

// ---------- K7: att softmax over N -> att_norms out; logits ----------
__global__ void k_fuse(const float* att_raw, const float* dotv,
                       const float* sp, void* out, const int* flagp) {
  int flag = flagp[0];
  int b = blockIdx.x;
  int t = threadIdx.x;
  __shared__ float red[256];
  float vals[16];
  float mx = -3.4e38f;
#pragma unroll
  for (int c = 0; c < 16; ++c) {
    vals[c] = att_raw[b * NN + c * 256 + t];
    mx = fmaxf(mx, vals[c]);
  }
  red[t] = mx;
  __syncthreads();
  for (int s = 128; s > 0; s >>= 1) {
    if (t < s) red[t] = fmaxf(red[t], red[t + s]);
    __syncthreads();
  }
  float M = red[0];
  __syncthreads();
  float sm = 0.f;
#pragma unroll
  for (int c = 0; c < 16; ++c) {
    vals[c] = __expf(vals[c] - M);
    sm += vals[c];
  }
  red[t] = sm;
  __syncthreads();
  for (int s = 128; s > 0; s >>= 1) {
    if (t < s) red[t] += red[t + s];
    __syncthreads();
  }
  float Z = red[0];
  __syncthreads();
  float acc = 0.f;
#pragma unroll
  for (int c = 0; c < 16; ++c) {
    int n = c * 256 + t;
    float a = vals[c] / Z;
    stv(out, 16 + b * NN + n, a, flag);
    acc += a * dotv[b * NN + n];
  }
  red[t] = acc;
  __syncthreads();
  for (int s = 128; s > 0; s >>= 1) {
    if (t < s) red[t] += red[t + s];
    __syncthreads();
  }
  if (t == 0) stv(out, b, red[0] + sp[769], flag);   // + out_b
}

// ---------- host ----------
extern "C" void kernel_launch(void* const* d_in, const int* in_sizes, int n_in,
                              void* d_out, int out_size, void* d_ws, size_t ws_size,
                              hipStream_t stream) {
  const int* head = (const int*)d_in[0];
  const int* tail = (const int*)d_in[1];
  const void* emb = d_in[2];
  const void* rela = d_in[3];
  const void* fcw = d_in[4];
  const void* fcb = d_in[5];
  const void* w1 = d_in[6];
  const void* b1 = d_in[7];
  const void* w2 = d_in[8];
  const void* b2 = d_in[9];
  const void* outw = d_in[10];
  const void* outb = d_in[11];

  float* ws = (float*)d_ws;
  int* flagp = (int*)d_ws;
  const size_t O_RELAT = 16;
  const size_t O_AF = O_RELAT + 16384;
  const size_t O_BF = O_AF + 262144;
  const size_t O_AH = O_BF + 262144;
  const size_t O_BH = O_AH + 262144;
  const size_t O_ATTR = O_BH + 262144;
  const size_t O_DOT = O_ATTR + 65536;
  const size_t O_SP = O_DOT + 65536;
  const size_t O_W1B = O_SP + 1024;        // 65536 bf16
  const size_t O_RWB = O_W1B + 32768;      // 16384 bf16
  const size_t O_NSB = O_RWB + 8192;       // 4.19M bf16
  const size_t O_TUP = O_NSB + 2097152;    // 16.8M bf16

  float* relaT = ws + O_RELAT;
  float* Af = ws + O_AF;
  float* Bf = ws + O_BF;
  float* Ah = ws + O_AH;
  float* Bh = ws + O_BH;
  float* attr = ws + O_ATTR;
  float* dotv = ws + O_DOT;
  float* sp = ws + O_SP;
  __hip_bfloat16* w1b = (__hip_bfloat16*)(ws + O_W1B);
  __hip_bfloat16* rwb = (__hip_bfloat16*)(ws + O_RWB);
  __hip_bfloat16* nsb = (__hip_bfloat16*)(ws + O_NSB);
  __hip_bfloat16* tup = (__hip_bfloat16*)(ws + O_TUP);

  hipLaunchKernelGGL(k_detect, dim3(1), dim3(256), 0, stream,
                     (const unsigned int*)emb, flagp);
  hipLaunchKernelGGL(k_prep, dim3(2369), dim3(256), 0, stream,
                     rela, relaT, b1, w2, outw, b2, outb, sp,
                     w1, w1b, head, tail, emb, Af, Bf, flagp);
  hipLaunchKernelGGL(k_premm, dim3(528), dim3(256), 0, stream,
                     Af, Bf, rela, fcw, fcb, Ah, Bh, rwb, flagp);
  hipLaunchKernelGGL(k_scores, dim3(1024), dim3(256), 0, stream,
                     Af, Bf, relaT, d_out, nsb, flagp);
  hipLaunchKernelGGL(k_tuple2, dim3(1024), dim3(256), 0, stream,
                     nsb, rwb, Ah, Bh, tup);
  hipLaunchKernelGGL(k_att2, dim3(512), dim3(256), 0, stream,
                     tup, w1b, sp, attr, dotv);
  hipLaunchKernelGGL(k_fuse, dim3(16), dim3(256), 0, stream,
                     attr, dotv, sp, d_out, flagp);
}